// Round 2
// baseline (1581.505 us; speedup 1.0000x reference)
//
#include <hip/hip_runtime.h>
#include <hip/hip_bf16.h>
#include <cstdint>
#include <cstddef>

// Problem constants
constexpr int NE  = 64;    // experts
constexpr int DM  = 1024;  // d_model
constexpr int DF  = 2048;  // d_ff
constexpr int CPE = 512;   // tokens per expert

typedef float  f32x4  __attribute__((ext_vector_type(4)));
typedef short  bf16x8 __attribute__((ext_vector_type(8)));

__device__ __forceinline__ short f2bf(float f) {
    union { __hip_bfloat16 h; short s; } u;
    u.h = __float2bfloat16(f);   // RNE
    return u.s;
}

__device__ __forceinline__ float gelu_tanh(float x) {
    // jax.nn.gelu default (approximate=True)
    float z = 0.7978845608028654f * (x + 0.044715f * x * x * x);
    float e = __expf(2.0f * z);
    float t = 1.0f - 2.0f / (e + 1.0f);
    return 0.5f * x * (1.0f + t);
}

// async 16B global -> LDS (lane-ordered: wave-uniform base + lane*16)
__device__ __forceinline__ void gld_lds16(const short* g, short* l) {
    __builtin_amdgcn_global_load_lds((const __attribute__((address_space(1))) void*)g,
                                     (__attribute__((address_space(3))) void*)l,
                                     16, 0, 0);
}

// ---------------- conversion kernels (BW-bound pre-pass) ----------------

// fp32 -> bf16 elementwise, 8 elems/thread
__global__ __launch_bounds__(256) void conv_cast(const float* __restrict__ X,
                                                 short* __restrict__ Xb) {
    size_t i = (size_t)blockIdx.x * 256 + threadIdx.x;
    const float4* p = (const float4*)X + 2 * i;
    float4 a = p[0], b = p[1];
    bf16x8 s;
    s[0] = f2bf(a.x); s[1] = f2bf(a.y); s[2] = f2bf(a.z); s[3] = f2bf(a.w);
    s[4] = f2bf(b.x); s[5] = f2bf(b.y); s[6] = f2bf(b.z); s[7] = f2bf(b.w);
    ((bf16x8*)Xb)[i] = s;
}

// W [E][K][N] fp32 -> WT [E][N][K] bf16, 64x64 tiles via LDS
template <int K, int N>
__global__ __launch_bounds__(256) void conv_transpose(const float* __restrict__ W,
                                                      short* __restrict__ WT) {
    constexpr int KT = K / 64, NT = N / 64;
    const int bid = blockIdx.x;
    const int e  = bid / (KT * NT);
    const int t  = bid % (KT * NT);
    const int k0 = (t % KT) * 64;
    const int n0 = (t / KT) * 64;

    __shared__ short tile[64 * 72];   // [n'][k'], row stride 72 shorts (144 B, 16B-mult)

    const float* src = W + ((size_t)e * K + k0) * (size_t)N + n0;
    const int tc = (threadIdx.x & 15) * 4;   // n' base
    const int tr = threadIdx.x >> 4;         // k' row group
#pragma unroll
    for (int p = 0; p < 4; ++p) {
        const int r = p * 16 + tr;
        float4 v = *(const float4*)(src + (size_t)r * N + tc);
        tile[(tc + 0) * 72 + r] = f2bf(v.x);
        tile[(tc + 1) * 72 + r] = f2bf(v.y);
        tile[(tc + 2) * 72 + r] = f2bf(v.z);
        tile[(tc + 3) * 72 + r] = f2bf(v.w);
    }
    __syncthreads();
    short* dst = WT + ((size_t)e * N + n0) * (size_t)K + k0;
    const int wk = (threadIdx.x & 7) * 8;
    const int wn = threadIdx.x >> 3;         // 0..31
#pragma unroll
    for (int p = 0; p < 2; ++p) {
        const int n = p * 32 + wn;
        *(uint4*)(dst + (size_t)n * K + wk) = *(const uint4*)&tile[n * 72 + wk];
    }
}

// ---------------- main bf16 GEMM, m97 structure ----------------
// C[e] = epi(A[e] @ BT[e]^T); A [M][K] bf16 (M = NE*CPE rows), BT [E][N][K] bf16.
// 128x128 tile, BK=64, 256 thr = 2x2 waves, wave = 4x4 of mfma 16x16x32.
// LDS: [2 panels][128 rows][32 k] per operand, unpadded (global_load_lds lane order);
// b128 frag reads sit at the inherent 8-way b128 floor.
template <int KTOT, int NTOT, bool GELU_OUT>
__global__ __launch_bounds__(256)
void gemm_bt(const short* __restrict__ A, const short* __restrict__ BT,
             void* __restrict__ C) {
    constexpr int NT = NTOT / 128;
    const int bid = blockIdx.x;
    const int e  = bid / (4 * NT);
    const int t  = bid % (4 * NT);
    const int mt = t & 3;      // fast: 4 M-blocks share the B panel in L2
    const int nt = t >> 2;

    __shared__ short As[8192];   // 2*128*32
    __shared__ short Bs[8192];

    const int tid = threadIdx.x, lane = tid & 63, w = tid >> 6;
    const int wm = w & 1, wn = w >> 1;

    const size_t arow0 = (size_t)e * CPE + (size_t)mt * 128;
    const short* Ae = A + arow0 * KTOT;
    const short* Be = BT + ((size_t)e * NTOT + (size_t)nt * 128) * KTOT;

    f32x4 acc[4][4];
#pragma unroll
    for (int i = 0; i < 4; ++i)
#pragma unroll
        for (int j = 0; j < 4; ++j) acc[i][j] = f32x4{0.f, 0.f, 0.f, 0.f};

    const int fr = lane & 15;
    const int fq = (lane >> 4) << 3;

    // per-lane global (row, kcol) for each of this wave's 4 staging chunks
    int rowS[4], colS[4];
#pragma unroll
    for (int i = 0; i < 4; ++i) {
        const int L = (w * 4 + i) * 512 + lane * 8;   // LDS short offset
        const int panel = L >> 12;
        const int rm = L & 4095;
        rowS[i] = rm >> 5;
        colS[i] = (panel << 5) + (L & 31);
    }

    for (int kk = 0; kk < KTOT; kk += 64) {
#pragma unroll
        for (int i = 0; i < 4; ++i) {
            const int c = w * 4 + i;
            gld_lds16(Ae + (size_t)rowS[i] * KTOT + kk + colS[i], As + c * 512);
            gld_lds16(Be + (size_t)rowS[i] * KTOT + kk + colS[i], Bs + c * 512);
        }
        __syncthreads();
#pragma unroll
        for (int p = 0; p < 2; ++p) {
            bf16x8 af[4], bfr[4];
#pragma unroll
            for (int i = 0; i < 4; ++i)
                af[i] = *(const bf16x8*)&As[p * 4096 + (wm * 64 + i * 16 + fr) * 32 + fq];
#pragma unroll
            for (int j = 0; j < 4; ++j)
                bfr[j] = *(const bf16x8*)&Bs[p * 4096 + (wn * 64 + j * 16 + fr) * 32 + fq];
#pragma unroll
            for (int i = 0; i < 4; ++i)
#pragma unroll
                for (int j = 0; j < 4; ++j)
                    acc[i][j] = __builtin_amdgcn_mfma_f32_16x16x32_bf16(af[i], bfr[j], acc[i][j], 0, 0, 0);
        }
        __syncthreads();
    }

    // epilogue: C/D layout col=lane&15, row=quad*4+reg (verified R1)
    const int lr = (lane >> 4) << 2;
    const int lc = lane & 15;
    const size_t crow0 = arow0 + (size_t)wm * 64;
    const int    ccol0 = nt * 128 + wn * 64;
#pragma unroll
    for (int i = 0; i < 4; ++i) {
#pragma unroll
        for (int r = 0; r < 4; ++r) {
            const size_t row = crow0 + i * 16 + lr + r;
#pragma unroll
            for (int j = 0; j < 4; ++j) {
                float v = acc[i][j][r];
                const size_t idx = row * (size_t)NTOT + ccol0 + j * 16 + lc;
                if constexpr (GELU_OUT) {
                    ((short*)C)[idx] = f2bf(gelu_tanh(v));
                } else {
                    ((float*)C)[idx] = v;
                }
            }
        }
    }
}

// ---------------- R1 fallback (in-kernel fp32 convert), used if ws too small ----------------
template <int KTOT, int NTOT, bool GELU_OUT, bool A_BF16>
__global__ __launch_bounds__(256)
void ffn_gemm(const void* __restrict__ Ag, const float* __restrict__ Bg, void* __restrict__ Cg)
{
    constexpr int BPE = (NTOT / 128) * 4;
    const int bid = blockIdx.x;
    const int e   = bid / BPE;
    const int t   = bid % BPE;
    const int mt  = t & 3;
    const int nt  = t >> 2;

    __shared__ short As[128 * 40];
    __shared__ short Bs[128 * 40];

    const int tid  = threadIdx.x;
    const int lane = tid & 63;
    const int wave = tid >> 6;
    const int wm   = wave & 1;
    const int wn   = wave >> 1;

    const int am = tid >> 1;
    const int ak = (tid & 1) << 4;
    const int bn = (tid & 63) << 1;
    const int bk = (tid >> 6) << 3;

    const size_t arow0 = (size_t)(e * CPE + mt * 128);
    const float* Bge = Bg + (size_t)e * KTOT * NTOT + nt * 128;

    f32x4 acc[4][4];
#pragma unroll
    for (int i = 0; i < 4; ++i)
#pragma unroll
        for (int j = 0; j < 4; ++j) acc[i][j] = f32x4{0.f, 0.f, 0.f, 0.f};

    const int fr = lane & 15;
    const int fq = (lane >> 4) << 3;

    for (int kk = 0; kk < KTOT; kk += 32) {
        if constexpr (A_BF16) {
            const short* Ab = (const short*)Ag + (arow0 + am) * (size_t)KTOT + kk + ak;
            uint4 v0 = *(const uint4*)(Ab);
            uint4 v1 = *(const uint4*)(Ab + 8);
            *(uint4*)&As[am * 40 + ak]     = v0;
            *(uint4*)&As[am * 40 + ak + 8] = v1;
        } else {
            const float* Af = (const float*)Ag + (arow0 + am) * (size_t)KTOT + kk + ak;
            float4 v0 = *(const float4*)(Af + 0);
            float4 v1 = *(const float4*)(Af + 4);
            float4 v2 = *(const float4*)(Af + 8);
            float4 v3 = *(const float4*)(Af + 12);
            bf16x8 s0, s1;
            s0[0]=f2bf(v0.x); s0[1]=f2bf(v0.y); s0[2]=f2bf(v0.z); s0[3]=f2bf(v0.w);
            s0[4]=f2bf(v1.x); s0[5]=f2bf(v1.y); s0[6]=f2bf(v1.z); s0[7]=f2bf(v1.w);
            s1[0]=f2bf(v2.x); s1[1]=f2bf(v2.y); s1[2]=f2bf(v2.z); s1[3]=f2bf(v2.w);
            s1[4]=f2bf(v3.x); s1[5]=f2bf(v3.y); s1[6]=f2bf(v3.z); s1[7]=f2bf(v3.w);
            *(bf16x8*)&As[am * 40 + ak]     = s0;
            *(bf16x8*)&As[am * 40 + ak + 8] = s1;
        }
        {
            const float* pb = Bge + (size_t)(kk + bk) * NTOT + bn;
            float2 bv[8];
#pragma unroll
            for (int j = 0; j < 8; ++j) bv[j] = *(const float2*)(pb + (size_t)j * NTOT);
            bf16x8 s0, s1;
#pragma unroll
            for (int j = 0; j < 8; ++j) { s0[j] = f2bf(bv[j].x); s1[j] = f2bf(bv[j].y); }
            *(bf16x8*)&Bs[(bn + 0) * 40 + bk] = s0;
            *(bf16x8*)&Bs[(bn + 1) * 40 + bk] = s1;
        }
        __syncthreads();

        bf16x8 af[4], bfr[4];
#pragma unroll
        for (int i = 0; i < 4; ++i)
            af[i] = *(const bf16x8*)&As[(wm * 64 + i * 16 + fr) * 40 + fq];
#pragma unroll
        for (int j = 0; j < 4; ++j)
            bfr[j] = *(const bf16x8*)&Bs[(wn * 64 + j * 16 + fr) * 40 + fq];
#pragma unroll
        for (int i = 0; i < 4; ++i)
#pragma unroll
            for (int j = 0; j < 4; ++j)
                acc[i][j] = __builtin_amdgcn_mfma_f32_16x16x32_bf16(af[i], bfr[j], acc[i][j], 0, 0, 0);
        __syncthreads();
    }

    const int lr = (lane >> 4) << 2;
    const int lc = lane & 15;
    const size_t crow0 = arow0 + wm * 64;
    const int    ccol0 = nt * 128 + wn * 64;
#pragma unroll
    for (int i = 0; i < 4; ++i) {
#pragma unroll
        for (int r = 0; r < 4; ++r) {
            const size_t row = crow0 + i * 16 + lr + r;
#pragma unroll
            for (int j = 0; j < 4; ++j) {
                float v = acc[i][j][r];
                const size_t idx = row * (size_t)NTOT + ccol0 + j * 16 + lc;
                if constexpr (GELU_OUT) {
                    ((__hip_bfloat16*)Cg)[idx] = __float2bfloat16(gelu_tanh(v));
                } else {
                    ((float*)Cg)[idx] = v;
                }
            }
        }
    }
}

extern "C" void kernel_launch(void* const* d_in, const int* in_sizes, int n_in,
                              void* d_out, int out_size, void* d_ws, size_t ws_size,
                              hipStream_t stream)
{
    (void)in_sizes; (void)n_in; (void)out_size;
    const float* X  = (const float*)d_in[0];   // [32768, 1024] fp32
    const float* W1 = (const float*)d_in[1];   // [64, 1024, 2048] fp32
    const float* W2 = (const float*)d_in[2];   // [64, 2048, 1024] fp32
    float*       Y  = (float*)d_out;           // [32768, 1024] fp32

    const size_t XB_B  = (size_t)NE * CPE * DM * 2;        //  64 MiB bf16 X
    const size_t W1T_B = (size_t)NE * DM * DF * 2;         // 256 MiB bf16 W1^T
    const size_t H_B   = (size_t)NE * CPE * DF * 2;        // 128 MiB bf16 H
    const size_t REQ   = XB_B + W1T_B + H_B;               // 448 MiB (W2^T overlays [0, XB+W1T))

    if (ws_size >= REQ) {
        short* Xb  = (short*)d_ws;
        short* W1t = (short*)((char*)d_ws + XB_B);
        short* W2t = (short*)d_ws;                          // reuses dead Xb+W1t region after gemm1
        short* H   = (short*)((char*)d_ws + XB_B + W1T_B);

        conv_cast<<<dim3((NE * CPE * DM) / (8 * 256)), dim3(256), 0, stream>>>(X, Xb);
        conv_transpose<DM, DF><<<dim3(NE * (DM / 64) * (DF / 64)), dim3(256), 0, stream>>>(W1, W1t);
        gemm_bt<DM, DF, true><<<dim3(NE * 4 * (DF / 128)), dim3(256), 0, stream>>>(Xb, W1t, (void*)H);
        conv_transpose<DF, DM><<<dim3(NE * (DF / 64) * (DM / 64)), dim3(256), 0, stream>>>(W2, W2t);
        gemm_bt<DF, DM, false><<<dim3(NE * 4 * (DM / 128)), dim3(256), 0, stream>>>(H, W2t, (void*)Y);
    } else {
        // R1 fallback: in-kernel conversion, needs only 128 MiB ws
        __hip_bfloat16* H = (__hip_bfloat16*)d_ws;
        ffn_gemm<DM, DF, true,  false><<<dim3(NE * 64), dim3(256), 0, stream>>>((const void*)X, W1, (void*)H);
        ffn_gemm<DF, DM, false, true ><<<dim3(NE * 32), dim3(256), 0, stream>>>((const void*)H, W2, (void*)Y);
    }
}